// Round 10
// baseline (149.301 us; speedup 1.0000x reference)
//
#include <hip/hip_runtime.h>

typedef short bf16x8 __attribute__((ext_vector_type(8)));
typedef float f32x2 __attribute__((ext_vector_type(2)));
typedef float f32x4 __attribute__((ext_vector_type(4)));
typedef float f32x16 __attribute__((ext_vector_type(16)));
typedef unsigned short ushort_t;
typedef unsigned short us8 __attribute__((ext_vector_type(8)));
typedef unsigned short us4 __attribute__((ext_vector_type(4)));
typedef unsigned int u32x4 __attribute__((ext_vector_type(4)));
typedef unsigned int uint2v __attribute__((ext_vector_type(2)));

#define MFMA16(a, b, c) __builtin_amdgcn_mfma_f32_16x16x32_bf16((a), (b), (c), 0, 0, 0)
#define MFMA32(a, b, c) __builtin_amdgcn_mfma_f32_32x32x16_bf16((a), (b), (c), 0, 0, 0)

template <int N> struct ic { static constexpr int value = N; };

static __device__ __forceinline__ ushort_t f2bf(float f) {
    unsigned int u = __builtin_bit_cast(unsigned int, f);
    u += 0x7FFFu + ((u >> 16) & 1u);   // RNE
    return (ushort_t)(u >> 16);
}

static __device__ __forceinline__ unsigned cvtpk(float lo, float hi) {
    unsigned r;
    asm("v_cvt_pk_bf16_f32 %0, %1, %2" : "=v"(r) : "v"(lo), "v"(hi));
    return r;
}

// global -> LDS direct async copy, 16B per lane (LDS dest = uniform base + lane*16)
static __device__ __forceinline__ void gload16(const void* g, void* l) {
    __builtin_amdgcn_global_load_lds(
        (const __attribute__((address_space(1))) unsigned int*)g,
        (__attribute__((address_space(3))) unsigned int*)l,
        16, 0, 0);
}

// ---------------------------------------------------------------------------
// Convert 4 fp32 512x512 weight matrices to bf16, packed consecutively.
// ---------------------------------------------------------------------------
__global__ __launch_bounds__(256) void cvt_w(const float* __restrict__ W0,
                                             const float* __restrict__ W1,
                                             const float* __restrict__ W2,
                                             const float* __restrict__ W3,
                                             ushort_t* __restrict__ dst) {
    const float* src = (blockIdx.y == 0) ? W0 : (blockIdx.y == 1) ? W1
                     : (blockIdx.y == 2) ? W2 : W3;
    const int i = (blockIdx.x * 256 + threadIdx.x) * 8;
    float4 f0 = *(const float4*)(src + i);
    float4 f1 = *(const float4*)(src + i + 4);
    unsigned tw[4] = {cvtpk(f0.x, f0.y), cvtpk(f0.z, f0.w),
                      cvtpk(f1.x, f1.y), cvtpk(f1.z, f1.w)};
    *(u32x4*)(dst + (size_t)blockIdx.y * 262144 + i) = *(u32x4*)tw;
}

// ---------------------------------------------------------------------------
// Fused Q/K/V projection NT-GEMM: grid (1024, 3).
// y=0: Q -> row-major [B*H][S][64], scaled by Cs.
// y=1: K -> chunk-ordered tiles (attn QK fragment = contiguous 1024B block).
// y=2: V -> chunk-ordered V^T tiles (attn PV fragment = contiguous 1024B).
// ---------------------------------------------------------------------------
__global__ __launch_bounds__(256) void gemm_qkv(const float* __restrict__ qi,
                                                const float* __restrict__ ki,
                                                const float* __restrict__ vi,
                                                const ushort_t* __restrict__ Wball,
                                                const float* __restrict__ bq,
                                                const float* __restrict__ bk,
                                                const float* __restrict__ bv,
                                                ushort_t* __restrict__ Qh,
                                                ushort_t* __restrict__ Kh,
                                                ushort_t* __restrict__ Vt,
                                                float Cs) {
    constexpr int K = 512;
    __shared__ ushort_t As[64][72];
    __shared__ ushort_t Bs[64][72];

    const int which = blockIdx.y;
    const float*    Ap   = (which == 0) ? qi : (which == 1) ? ki : vi;
    const ushort_t* Wb   = Wball + (size_t)which * 262144;
    const float*    bias = (which == 0) ? bq : (which == 1) ? bk : bv;
    ushort_t*       outp = (which == 0) ? Qh : (which == 1) ? Kh : Vt;

    int bid = blockIdx.x;
    bid = (bid & 7) * 128 + (bid >> 3);   // XCD-affine bijective remap (nwg=1024)
    const int bm = bid >> 3;
    const int bn = bid & 7;
    const int m0 = bm * 64, n0 = bn * 64;
    const int t    = threadIdx.x;
    const int lane = t & 63;
    const int wv   = t >> 6;
    const int wm   = wv >> 1, wn = wv & 1;
    const int lrow = t >> 2;
    const int lcol = (t & 3) * 16;

    const int l15 = lane & 15;
    const int l16 = lane >> 4;

    f32x4 acc[2][2] = {};

    const float*    apf = Ap + (size_t)(m0 + lrow) * K + lcol;
    const ushort_t* bpb = Wb + (size_t)(n0 + lrow) * K + lcol;

    us8 br0, br1;
    f32x4 af[4];

    af[0] = *(const f32x4*)apf;       af[1] = *(const f32x4*)(apf + 4);
    af[2] = *(const f32x4*)(apf + 8); af[3] = *(const f32x4*)(apf + 12);
    br0 = *(const us8*)bpb; br1 = *(const us8*)(bpb + 8);

#pragma unroll 1
    for (int kt = 0; kt < K / 64; ++kt) {
        __syncthreads();
        {
            unsigned tw[8];
#pragma unroll
            for (int i = 0; i < 4; ++i) {
                tw[2 * i]     = cvtpk(af[i][0], af[i][1]);
                tw[2 * i + 1] = cvtpk(af[i][2], af[i][3]);
            }
            *(u32x4*)&As[lrow][lcol]     = *(u32x4*)tw;
            *(u32x4*)&As[lrow][lcol + 8] = *(u32x4*)(tw + 4);
        }
        *(us8*)&Bs[lrow][lcol]     = br0;
        *(us8*)&Bs[lrow][lcol + 8] = br1;
        __syncthreads();

        if (kt < K / 64 - 1) {
            const int off = (kt + 1) * 64;
            const float* s = apf + off;
            af[0] = *(const f32x4*)s;       af[1] = *(const f32x4*)(s + 4);
            af[2] = *(const f32x4*)(s + 8); af[3] = *(const f32x4*)(s + 12);
            br0 = *(const us8*)(bpb + off); br1 = *(const us8*)(bpb + off + 8);
        }

#pragma unroll
        for (int kk = 0; kk < 2; ++kk) {
            bf16x8 a0 = *(const bf16x8*)&As[wm * 32 + l15][kk * 32 + l16 * 8];
            bf16x8 a1 = *(const bf16x8*)&As[wm * 32 + 16 + l15][kk * 32 + l16 * 8];
            bf16x8 b0 = *(const bf16x8*)&Bs[wn * 32 + l15][kk * 32 + l16 * 8];
            bf16x8 b1 = *(const bf16x8*)&Bs[wn * 32 + 16 + l15][kk * 32 + l16 * 8];
            acc[0][0] = MFMA16(a0, b0, acc[0][0]);
            acc[0][1] = MFMA16(a0, b1, acc[0][1]);
            acc[1][0] = MFMA16(a1, b0, acc[1][0]);
            acc[1][1] = MFMA16(a1, b1, acc[1][1]);
        }
    }

#pragma unroll
    for (int i = 0; i < 2; ++i)
#pragma unroll
        for (int j = 0; j < 2; ++j) {
            const int n  = n0 + wn * 32 + j * 16 + l15;
            const float bv_ = bias[n];
            const int h = n >> 6, d = n & 63;
            if (which == 2) {
                // V^T chunk-ordered: 4 consecutive keys stay in one 8-chunk
                const int mbase = m0 + wm * 32 + i * 16 + l16 * 4;
                const int b = mbase >> 12, key = mbase & 4095;
                const int keyr = key & 63;
                const int ks = keyr >> 4, hc = (keyr >> 3) & 1, e0 = keyr & 7;
                const int db = d >> 5, dr = d & 31;
                ushort_t tmp[4];
#pragma unroll
                for (int v = 0; v < 4; ++v) tmp[v] = f2bf(acc[i][j][v] + bv_);
                *(us4*)(outp + (size_t)(b * 8 + h) * 262144 +
                        (size_t)(key >> 6) * 4096 +
                        db * 2048 + ks * 512 + (hc * 32 + dr) * 8 + e0) = *(us4*)tmp;
            } else if (which == 1) {
                // K chunk-ordered scalar stores
                const int jd = d >> 4, hc = (d >> 3) & 1, e = d & 7;
#pragma unroll
                for (int v = 0; v < 4; ++v) {
                    const int m = m0 + wm * 32 + i * 16 + l16 * 4 + v;
                    const int b = m >> 12, s = m & 4095;
                    const int r = s & 63, kb2 = r >> 5, kr = r & 31;
                    outp[(size_t)(b * 8 + h) * 262144 + (size_t)(s >> 6) * 4096 +
                         kb2 * 2048 + jd * 512 + (hc * 32 + kr) * 8 + e] =
                        f2bf(acc[i][j][v] + bv_);
                }
            } else {
#pragma unroll
                for (int v = 0; v < 4; ++v) {
                    const int m = m0 + wm * 32 + i * 16 + l16 * 4 + v;
                    const int b = m >> 12, s = m & 4095;
                    outp[(((size_t)(b * 8 + h)) * 4096 + s) * 64 + d] =
                        f2bf((acc[i][j][v] + bv_) * Cs);
                }
            }
        }
}

// ---------------------------------------------------------------------------
// Output NT-GEMM: A bf16 [M][512], W bf16, out fp32 [M][512].
// ---------------------------------------------------------------------------
__global__ __launch_bounds__(256) void gemm_out(const ushort_t* __restrict__ Ap,
                                                const ushort_t* __restrict__ Wb,
                                                const float* __restrict__ bias,
                                                float* __restrict__ outp) {
    constexpr int K = 512;
    __shared__ ushort_t As[64][72];
    __shared__ ushort_t Bs[64][72];

    int bid = blockIdx.x;
    bid = (bid & 7) * 128 + (bid >> 3);
    const int bm = bid >> 3;
    const int bn = bid & 7;
    const int m0 = bm * 64, n0 = bn * 64;
    const int t    = threadIdx.x;
    const int lane = t & 63;
    const int wv   = t >> 6;
    const int wm   = wv >> 1, wn = wv & 1;
    const int lrow = t >> 2;
    const int lcol = (t & 3) * 16;

    const int l15 = lane & 15;
    const int l16 = lane >> 4;

    f32x4 acc[2][2] = {};

    const ushort_t* apb = Ap + (size_t)(m0 + lrow) * K + lcol;
    const ushort_t* bpb = Wb + (size_t)(n0 + lrow) * K + lcol;

    us8 ar0, ar1, br0, br1;
    ar0 = *(const us8*)apb; ar1 = *(const us8*)(apb + 8);
    br0 = *(const us8*)bpb; br1 = *(const us8*)(bpb + 8);

#pragma unroll 1
    for (int kt = 0; kt < K / 64; ++kt) {
        __syncthreads();
        *(us8*)&As[lrow][lcol]     = ar0;
        *(us8*)&As[lrow][lcol + 8] = ar1;
        *(us8*)&Bs[lrow][lcol]     = br0;
        *(us8*)&Bs[lrow][lcol + 8] = br1;
        __syncthreads();

        if (kt < K / 64 - 1) {
            const int off = (kt + 1) * 64;
            ar0 = *(const us8*)(apb + off); ar1 = *(const us8*)(apb + off + 8);
            br0 = *(const us8*)(bpb + off); br1 = *(const us8*)(bpb + off + 8);
        }

#pragma unroll
        for (int kk = 0; kk < 2; ++kk) {
            bf16x8 a0 = *(const bf16x8*)&As[wm * 32 + l15][kk * 32 + l16 * 8];
            bf16x8 a1 = *(const bf16x8*)&As[wm * 32 + 16 + l15][kk * 32 + l16 * 8];
            bf16x8 b0 = *(const bf16x8*)&Bs[wn * 32 + l15][kk * 32 + l16 * 8];
            bf16x8 b1 = *(const bf16x8*)&Bs[wn * 32 + 16 + l15][kk * 32 + l16 * 8];
            acc[0][0] = MFMA16(a0, b0, acc[0][0]);
            acc[0][1] = MFMA16(a0, b1, acc[0][1]);
            acc[1][0] = MFMA16(a1, b0, acc[1][0]);
            acc[1][1] = MFMA16(a1, b1, acc[1][1]);
        }
    }

#pragma unroll
    for (int i = 0; i < 2; ++i)
#pragma unroll
        for (int j = 0; j < 2; ++j) {
            const int n  = n0 + wn * 32 + j * 16 + l15;
            const float bv_ = bias[n];
#pragma unroll
            for (int v = 0; v < 4; ++v) {
                const int m = m0 + wm * 32 + i * 16 + l16 * 4 + v;
                outp[(size_t)m * 512 + n] = acc[i][j][v] + bv_;
            }
        }
}

// ---------------------------------------------------------------------------
// Flash attention, swapped-QK^T 32x32, zero-shift softmax, chunk-ordered K/V
// with global_load_lds staging (bank-conflict-free, immediate-offset reads).
// 1D grid with XCD-affine mapping: xcd = id&7 owns 2 bh entirely ->
// per-XCD K/V working set 2MB <= 4MB L2.
// PARTIAL: KV-split x2 (half the keys per block, fp32 O/l partials).
// ---------------------------------------------------------------------------
template <bool PARTIAL>
__global__ __launch_bounds__(256) void attn_fwd(const ushort_t* __restrict__ Qh,
                                                const ushort_t* __restrict__ Kg,
                                                const ushort_t* __restrict__ Vg,
                                                ushort_t* __restrict__ Out,
                                                float* __restrict__ Op,
                                                float* __restrict__ Lp) {
    constexpr int S  = 4096;
    constexpr int NT = PARTIAL ? 32 : 64;
    __shared__ __attribute__((aligned(16))) char LDS[32768];

    // XCD-affine decode
    const int id   = blockIdx.x;
    const int xcd  = id & 7;
    const int slot = id >> 3;            // PARTIAL: 0..127, else 0..63
    const int qt   = slot & 31;
    const int half = PARTIAL ? ((slot >> 5) & 1) : 0;
    const int bh   = PARTIAL ? (xcd * 2 + (slot >> 6)) : (xcd * 2 + (slot >> 5));
    const int b    = bh >> 3, h = bh & 7;

    const int t    = threadIdx.x;
    const int lane = t & 63;
    const int wv   = t >> 6;
    const int l31  = lane & 31;
    const int hl   = lane >> 5;

    const int qw = qt * 128 + wv * 32;

    // Q fragments (B operand): col=q=l31, k = ds*16 + 8*hl + j
    bf16x8 qf[4];
    {
        const ushort_t* qp = Qh + ((size_t)bh * S + qw + l31) * 64 + hl * 8;
#pragma unroll
        for (int ds = 0; ds < 4; ++ds) qf[ds] = *(const bf16x8*)(qp + ds * 16);
    }

    const f32x16 fzero = {};
    f32x16 accO[2] = {};
    float ll = 0.f;

    const char* lbase = LDS + lane * 16;   // single loop-invariant read address
    const int wvb = wv * 1024;
    const size_t tile0 = (size_t)half * 32 * 4096;
    const ushort_t* kg = Kg + (size_t)bh * 262144 + tile0 + wv * 512 + lane * 8;
    const ushort_t* vg = Vg + (size_t)bh * 262144 + tile0 + wv * 512 + lane * 8;

    auto issue = [&](int kt, auto curc) {
        constexpr int CUR = decltype(curc)::value;
        const ushort_t* kg_ = kg + (size_t)kt * 4096;
        const ushort_t* vg_ = vg + (size_t)kt * 4096;
        gload16(kg_,        LDS + CUR * 8192 + wvb);
        gload16(kg_ + 2048, LDS + CUR * 8192 + 4096 + wvb);
        gload16(vg_,        LDS + 16384 + CUR * 8192 + wvb);
        gload16(vg_ + 2048, LDS + 16384 + CUR * 8192 + 4096 + wvb);
    };

    auto tile = [&](int kt, auto curc) {
        constexpr int CUR = decltype(curc)::value;

        // QK^T -> S^T[key][q]; C seeded with inline zero.
        f32x16 sc0, sc1;
        __builtin_amdgcn_s_setprio(1);
        {
            bf16x8 kf = *(const bf16x8*)(lbase + CUR * 8192);
            sc0 = MFMA32(kf, qf[0], fzero);
        }
#pragma unroll
        for (int ds = 1; ds < 4; ++ds) {
            bf16x8 kf = *(const bf16x8*)(lbase + CUR * 8192 + ds * 1024);
            sc0 = MFMA32(kf, qf[ds], sc0);
        }
        {
            bf16x8 kf = *(const bf16x8*)(lbase + CUR * 8192 + 4096);
            sc1 = MFMA32(kf, qf[0], fzero);
        }
#pragma unroll
        for (int ds = 1; ds < 4; ++ds) {
            bf16x8 kf = *(const bf16x8*)(lbase + CUR * 8192 + 4096 + ds * 1024);
            sc1 = MFMA32(kf, qf[ds], sc1);
        }
        __builtin_amdgcn_s_setprio(0);

        // P = exp2(S)
#pragma unroll
        for (int i = 0; i < 16; ++i) {
            sc0[i] = __builtin_amdgcn_exp2f(sc0[i]);
            sc1[i] = __builtin_amdgcn_exp2f(sc1[i]);
        }

        // l partial sum via packed-pair tree
        {
#define PAIR(v, i) __builtin_shufflevector((v), (v), 2 * (i), 2 * (i) + 1)
            f32x2 pa  = (PAIR(sc0, 0) + PAIR(sc0, 1)) + (PAIR(sc0, 2) + PAIR(sc0, 3));
            f32x2 pbt = (PAIR(sc0, 4) + PAIR(sc0, 5)) + (PAIR(sc0, 6) + PAIR(sc0, 7));
            f32x2 pc  = (PAIR(sc1, 0) + PAIR(sc1, 1)) + (PAIR(sc1, 2) + PAIR(sc1, 3));
            f32x2 pd  = (PAIR(sc1, 4) + PAIR(sc1, 5)) + (PAIR(sc1, 6) + PAIR(sc1, 7));
            f32x2 s2  = (pa + pbt) + (pc + pd);
            ll += s2.x + s2.y;
#undef PAIR
        }

        // pack P^T B-fragments in-register
        bf16x8 pb[4];
#pragma unroll
        for (int ks = 0; ks < 4; ++ks) {
            const int R0 = (ks & 1) * 8;
            float e0, e1, e2, e3, e4, e5, e6, e7;
            if (ks < 2) {
                e0 = sc0[R0+0]; e1 = sc0[R0+1]; e2 = sc0[R0+2]; e3 = sc0[R0+3];
                e4 = sc0[R0+4]; e5 = sc0[R0+5]; e6 = sc0[R0+6]; e7 = sc0[R0+7];
            } else {
                e0 = sc1[R0+0]; e1 = sc1[R0+1]; e2 = sc1[R0+2]; e3 = sc1[R0+3];
                e4 = sc1[R0+4]; e5 = sc1[R0+5]; e6 = sc1[R0+6]; e7 = sc1[R0+7];
            }
            unsigned w0 = cvtpk(e0, e1);
            unsigned w1 = cvtpk(e2, e3);
            unsigned w2 = cvtpk(e4, e5);
            unsigned w3 = cvtpk(e6, e7);
            uint2v s02 = __builtin_amdgcn_permlane32_swap(w0, w2, false, false);
            uint2v s13 = __builtin_amdgcn_permlane32_swap(w1, w3, false, false);
            u32x4 w = {s02.x, s13.x, s02.y, s13.y};
            pb[ks] = __builtin_bit_cast(bf16x8, w);
        }

        // PV: O^T[d][q] += V^T[d][k] * P^T[k][q]
        __builtin_amdgcn_s_setprio(1);
#pragma unroll
        for (int ks = 0; ks < 4; ++ks) {
            {
                bf16x8 vf = *(const bf16x8*)(lbase + 16384 + CUR * 8192 + ks * 1024);
                accO[0] = MFMA32(vf, pb[ks], accO[0]);
            }
            {
                bf16x8 vf = *(const bf16x8*)(lbase + 16384 + CUR * 8192 + 4096 + ks * 1024);
                accO[1] = MFMA32(vf, pb[ks], accO[1]);
            }
        }
        __builtin_amdgcn_s_setprio(0);

        // all waves done reading buf CUR -> refill it for kt+2
        __syncthreads();
        if (kt + 2 < NT) issue(kt + 2, curc);
    };

    issue(0, ic<0>{});
    issue(1, ic<1>{});
    __syncthreads();   // compiler drains vmcnt here; both buffers ready

#pragma unroll 1
    for (int kt2 = 0; kt2 < NT; kt2 += 2) {
        tile(kt2,     ic<0>{});
        tile(kt2 + 1, ic<1>{});
    }

    const float lt = ll + __shfl_xor(ll, 32);

    if constexpr (PARTIAL) {
        const size_t pb_ = (size_t)(half * 16 + bh) * 4096 + qw + l31;
        float* op = Op + pb_ * 64;
#pragma unroll
        for (int db = 0; db < 2; ++db)
#pragma unroll
            for (int q4 = 0; q4 < 4; ++q4) {
                float4 tmp = {accO[db][q4 * 4 + 0], accO[db][q4 * 4 + 1],
                              accO[db][q4 * 4 + 2], accO[db][q4 * 4 + 3]};
                *(float4*)(op + db * 32 + q4 * 8 + hl * 4) = tmp;
            }
        if (hl == 0) Lp[pb_] = lt;
    } else {
        const float inv = 1.0f / lt;
        ushort_t* orow = Out + ((size_t)b * S + qw + l31) * 512 + h * 64;
#pragma unroll
        for (int db = 0; db < 2; ++db)
#pragma unroll
            for (int q4 = 0; q4 < 4; ++q4) {
                unsigned w0 = cvtpk(accO[db][q4 * 4 + 0] * inv, accO[db][q4 * 4 + 1] * inv);
                unsigned w1 = cvtpk(accO[db][q4 * 4 + 2] * inv, accO[db][q4 * 4 + 3] * inv);
                unsigned tmp[2] = {w0, w1};
                *(us4*)(orow + db * 32 + q4 * 8 + hl * 4) = *(const us4*)tmp;
            }
    }
}

// ---------------------------------------------------------------------------
// Merge halves (zero shift): O = (O0 + O1) / (l0 + l1).
// ---------------------------------------------------------------------------
__global__ __launch_bounds__(256) void attn_merge(const float* __restrict__ Op,
                                                  const float* __restrict__ Lp,
                                                  ushort_t* __restrict__ Out) {
    const int bh = blockIdx.x;
    const int b  = bh >> 3, h = bh & 7;
    const int q  = blockIdx.y * 32 + (threadIdx.x >> 3);
    const int d0 = (threadIdx.x & 7) * 8;
    const size_t i0 = (size_t)bh * 4096 + q;
    const size_t i1 = i0 + 16 * 4096;
    const float inv = 1.0f / (Lp[i0] + Lp[i1]);
    const float* p0 = Op + i0 * 64 + d0;
    const float* p1 = Op + i1 * 64 + d0;
    f32x4 x0 = *(const f32x4*)p0, x1 = *(const f32x4*)(p0 + 4);
    f32x4 y0 = *(const f32x4*)p1, y1 = *(const f32x4*)(p1 + 4);
    unsigned tw[4];
    tw[0] = cvtpk((x0[0] + y0[0]) * inv, (x0[1] + y0[1]) * inv);
    tw[1] = cvtpk((x0[2] + y0[2]) * inv, (x0[3] + y0[3]) * inv);
    tw[2] = cvtpk((x1[0] + y1[0]) * inv, (x1[1] + y1[1]) * inv);
    tw[3] = cvtpk((x1[2] + y1[2]) * inv, (x1[3] + y1[3]) * inv);
    *(u32x4*)(Out + ((size_t)b * 4096 + q) * 512 + h * 64 + d0) = *(u32x4*)tw;
}

// ---------------------------------------------------------------------------
extern "C" void kernel_launch(void* const* d_in, const int* in_sizes, int n_in,
                              void* d_out, int out_size, void* d_ws, size_t ws_size,
                              hipStream_t stream) {
    const float* q  = (const float*)d_in[0];
    const float* k  = (const float*)d_in[1];
    const float* v  = (const float*)d_in[2];
    const float* Wq = (const float*)d_in[3];
    const float* bq = (const float*)d_in[4];
    const float* bk = (const float*)d_in[6];
    const float* bv = (const float*)d_in[8];
    const float* bo = (const float*)d_in[10];

    char* w = (char*)d_ws;
    const size_t SZ     = (size_t)2 * 8 * 4096 * 64 * 2;        // 8 MB
    const size_t OFF_WB = 4 * SZ;                               // 32 MB
    const size_t OFF_OP = OFF_WB + 2 * 1024 * 1024;             // 34 MB
    const size_t OFF_LP = OFF_OP + (size_t)2 * 16 * 4096 * 64 * 4;  // +32 MB
    const size_t TOTAL  = OFF_LP + (size_t)2 * 16 * 4096 * 4;       // +0.5 MB

    ushort_t* Qh  = (ushort_t*)(w);
    ushort_t* Kh  = (ushort_t*)(w + SZ);
    ushort_t* Vtr = (ushort_t*)(w + 2 * SZ);
    ushort_t* AO  = (ushort_t*)(w + 3 * SZ);
    ushort_t* Wb  = (ushort_t*)(w + OFF_WB);
    float*    Opr = (float*)(w + OFF_OP);
    float*    Lpr = (float*)(w + OFF_LP);

    const bool split = ws_size >= TOTAL;

    cvt_w<<<dim3(128, 4), 256, 0, stream>>>(Wq, (const float*)d_in[5],
                                            (const float*)d_in[7], (const float*)d_in[9], Wb);

    const float Cs = 0.125f * 1.44269504f;  // softmax scale * log2(e), folded into Q
    gemm_qkv<<<dim3(1024, 3), 256, 0, stream>>>(q, k, v, Wb, bq, bk, bv, Qh, Kh, Vtr, Cs);

    if (split) {
        attn_fwd<true><<<1024, 256, 0, stream>>>(Qh, Kh, Vtr, AO, Opr, Lpr);
        attn_merge<<<dim3(16, 128), 256, 0, stream>>>(Opr, Lpr, AO);
    } else {
        attn_fwd<false><<<512, 256, 0, stream>>>(Qh, Kh, Vtr, AO, nullptr, nullptr);
    }

    gemm_out<<<1024, 256, 0, stream>>>(AO, Wb + 3 * 262144, bo, (float*)d_out);
}

// Round 11
// 147.719 us; speedup vs baseline: 1.0107x; 1.0107x over previous
//
#include <hip/hip_runtime.h>

typedef short bf16x8 __attribute__((ext_vector_type(8)));
typedef float f32x4 __attribute__((ext_vector_type(4)));
typedef float f32x16 __attribute__((ext_vector_type(16)));
typedef unsigned short ushort_t;
typedef unsigned short us8 __attribute__((ext_vector_type(8)));
typedef unsigned short us4 __attribute__((ext_vector_type(4)));
typedef unsigned int u32x4 __attribute__((ext_vector_type(4)));
typedef unsigned int uint2v __attribute__((ext_vector_type(2)));

#define MFMA16(a, b, c) __builtin_amdgcn_mfma_f32_16x16x32_bf16((a), (b), (c), 0, 0, 0)
#define MFMA32(a, b, c) __builtin_amdgcn_mfma_f32_32x32x16_bf16((a), (b), (c), 0, 0, 0)

template <int N> struct ic { static constexpr int value = N; };

static __device__ __forceinline__ ushort_t f2bf(float f) {
    unsigned int u = __builtin_bit_cast(unsigned int, f);
    u += 0x7FFFu + ((u >> 16) & 1u);   // RNE
    return (ushort_t)(u >> 16);
}

static __device__ __forceinline__ unsigned cvtpk(float lo, float hi) {
    unsigned r;
    asm("v_cvt_pk_bf16_f32 %0, %1, %2" : "=v"(r) : "v"(lo), "v"(hi));
    return r;
}

// global -> LDS direct async copy, 16B per lane (LDS dest = wave-uniform base + lane*16)
static __device__ __forceinline__ void gload16(const void* g, void* l) {
    __builtin_amdgcn_global_load_lds(
        (const __attribute__((address_space(1))) unsigned int*)g,
        (__attribute__((address_space(3))) unsigned int*)l,
        16, 0, 0);
}

// ---------------------------------------------------------------------------
// Convert 4 fp32 512x512 weight matrices to bf16, packed consecutively.
// ---------------------------------------------------------------------------
__global__ __launch_bounds__(256) void cvt_w(const float* __restrict__ W0,
                                             const float* __restrict__ W1,
                                             const float* __restrict__ W2,
                                             const float* __restrict__ W3,
                                             ushort_t* __restrict__ dst) {
    const float* src = (blockIdx.y == 0) ? W0 : (blockIdx.y == 1) ? W1
                     : (blockIdx.y == 2) ? W2 : W3;
    const int i = (blockIdx.x * 256 + threadIdx.x) * 8;
    float4 f0 = *(const float4*)(src + i);
    float4 f1 = *(const float4*)(src + i + 4);
    unsigned tw[4] = {cvtpk(f0.x, f0.y), cvtpk(f0.z, f0.w),
                      cvtpk(f1.x, f1.y), cvtpk(f1.z, f1.w)};
    *(u32x4*)(dst + (size_t)blockIdx.y * 262144 + i) = *(u32x4*)tw;
}

// ---------------------------------------------------------------------------
// Fused Q/K/V projection, m97-style 128x128 tile, BK=32, grid (256, 3).
// A (fp32) is reg-staged + cvt_pk -> ds_write; B (bf16 weights) staged via
// global_load_lds width-16 (linear [128][32] image). 4 waves (2x2), each
// owning a 64x64 quadrant: acc[4][4] of 16x16x32 frags.
// Epilogues (abs (m,n) formulas identical to verified r9):
//   y=0: Q row-major [B*H][S][64] scaled by Cs
//   y=1: K chunk-ordered tiles (attn QK frag = contiguous 1024B)
//   y=2: V^T chunk-ordered tiles (attn PV frag = contiguous 1024B)
// ---------------------------------------------------------------------------
__global__ __launch_bounds__(256) void gemm_qkv(const float* __restrict__ qi,
                                                const float* __restrict__ ki,
                                                const float* __restrict__ vi,
                                                const ushort_t* __restrict__ Wball,
                                                const float* __restrict__ bq,
                                                const float* __restrict__ bk,
                                                const float* __restrict__ bv,
                                                ushort_t* __restrict__ Qh,
                                                ushort_t* __restrict__ Kh,
                                                ushort_t* __restrict__ Vt,
                                                float Cs) {
    __shared__ __attribute__((aligned(16))) ushort_t As[128][32];
    __shared__ __attribute__((aligned(16))) ushort_t Bs[128][32];

    const int which = blockIdx.y;
    const float*    Ap   = (which == 0) ? qi : (which == 1) ? ki : vi;
    const ushort_t* Wb   = Wball + (size_t)which * 262144;
    const float*    bias = (which == 0) ? bq : (which == 1) ? bk : bv;
    ushort_t*       outp = (which == 0) ? Qh : (which == 1) ? Kh : Vt;

    const int bid = blockIdx.x;
    const int rid = (bid & 7) * 32 + (bid >> 3);   // XCD-affine bijective (nwg=256)
    const int bm  = rid >> 2, bn = rid & 3;
    const int m0  = bm * 128, n0 = bn * 128;

    const int t    = threadIdx.x;
    const int lane = t & 63;
    const int wv   = t >> 6;
    const int wm   = wv >> 1, wn = wv & 1;
    const int l15  = lane & 15, l16 = lane >> 4;
    const int srow = t >> 2;          // 0..63
    const int scol = (t & 3) * 8;     // 0,8,16,24

    f32x4 acc[4][4] = {};

    const float*    a0p = Ap + (size_t)(m0 + srow) * 512 + scol;
    const float*    a1p = a0p + (size_t)64 * 512;
    const ushort_t* b0p = Wb + (size_t)(n0 + srow) * 512 + scol;
    const ushort_t* b1p = b0p + (size_t)64 * 512;

    f32x4 ar[4];
    ar[0] = *(const f32x4*)a0p; ar[1] = *(const f32x4*)(a0p + 4);
    ar[2] = *(const f32x4*)a1p; ar[3] = *(const f32x4*)(a1p + 4);

#pragma unroll 1
    for (int kt = 0; kt < 16; ++kt) {
        __syncthreads();   // previous compute done reading LDS
        {
            unsigned t0[4] = {cvtpk(ar[0][0], ar[0][1]), cvtpk(ar[0][2], ar[0][3]),
                              cvtpk(ar[1][0], ar[1][1]), cvtpk(ar[1][2], ar[1][3])};
            *(u32x4*)&As[srow][scol] = *(u32x4*)t0;
            unsigned t1[4] = {cvtpk(ar[2][0], ar[2][1]), cvtpk(ar[2][2], ar[2][3]),
                              cvtpk(ar[3][0], ar[3][1]), cvtpk(ar[3][2], ar[3][3])};
            *(u32x4*)&As[64 + srow][scol] = *(u32x4*)t1;
        }
        gload16(b0p + kt * 32, (char*)Bs + wv * 1024);
        gload16(b1p + kt * 32, (char*)Bs + 4096 + wv * 1024);
        __syncthreads();   // A ds_writes visible + B gloads landed

        if (kt < 15) {     // prefetch next A chunk into regs during compute
            const float* an0 = a0p + (kt + 1) * 32;
            const float* an1 = a1p + (kt + 1) * 32;
            ar[0] = *(const f32x4*)an0; ar[1] = *(const f32x4*)(an0 + 4);
            ar[2] = *(const f32x4*)an1; ar[3] = *(const f32x4*)(an1 + 4);
        }

        bf16x8 af[4], bf[4];
#pragma unroll
        for (int i = 0; i < 4; ++i)
            af[i] = *(const bf16x8*)&As[wm * 64 + i * 16 + l15][l16 * 8];
#pragma unroll
        for (int j = 0; j < 4; ++j)
            bf[j] = *(const bf16x8*)&Bs[wn * 64 + j * 16 + l15][l16 * 8];
#pragma unroll
        for (int i = 0; i < 4; ++i)
#pragma unroll
            for (int j = 0; j < 4; ++j)
                acc[i][j] = MFMA16(af[i], bf[j], acc[i][j]);
    }

#pragma unroll
    for (int i = 0; i < 4; ++i)
#pragma unroll
        for (int j = 0; j < 4; ++j) {
            const int n  = n0 + wn * 64 + j * 16 + l15;
            const float bv_ = bias[n];
            const int h = n >> 6, d = n & 63;
            if (which == 2) {
                const int mbase = m0 + wm * 64 + i * 16 + l16 * 4;
                const int b = mbase >> 12, key = mbase & 4095;
                const int keyr = key & 63;
                const int ks = keyr >> 4, hc = (keyr >> 3) & 1, e0 = keyr & 7;
                const int db = d >> 5, dr = d & 31;
                ushort_t tmp[4];
#pragma unroll
                for (int v = 0; v < 4; ++v) tmp[v] = f2bf(acc[i][j][v] + bv_);
                *(us4*)(outp + (size_t)(b * 8 + h) * 262144 +
                        (size_t)(key >> 6) * 4096 +
                        db * 2048 + ks * 512 + (hc * 32 + dr) * 8 + e0) = *(us4*)tmp;
            } else if (which == 1) {
                const int jd = d >> 4, hc = (d >> 3) & 1, e = d & 7;
#pragma unroll
                for (int v = 0; v < 4; ++v) {
                    const int m = m0 + wm * 64 + i * 16 + l16 * 4 + v;
                    const int b = m >> 12, s = m & 4095;
                    const int r = s & 63, kb2 = r >> 5, kr = r & 31;
                    outp[(size_t)(b * 8 + h) * 262144 + (size_t)(s >> 6) * 4096 +
                         kb2 * 2048 + jd * 512 + (hc * 32 + kr) * 8 + e] =
                        f2bf(acc[i][j][v] + bv_);
                }
            } else {
#pragma unroll
                for (int v = 0; v < 4; ++v) {
                    const int m = m0 + wm * 64 + i * 16 + l16 * 4 + v;
                    const int b = m >> 12, s = m & 4095;
                    outp[(((size_t)(b * 8 + h)) * 4096 + s) * 64 + d] =
                        f2bf((acc[i][j][v] + bv_) * Cs);
                }
            }
        }
}

// ---------------------------------------------------------------------------
// Output NT-GEMM: 128x64 tile, BK=32, grid 512. A (bf16 [8192][512]) and
// B (bf16 weights) both staged via global_load_lds — zero staging VALU.
// 4 waves (2x2), wave tile 64x32, acc[4][2].
// ---------------------------------------------------------------------------
__global__ __launch_bounds__(256) void gemm_out(const ushort_t* __restrict__ Ap,
                                                const ushort_t* __restrict__ Wb,
                                                const float* __restrict__ bias,
                                                float* __restrict__ outp) {
    __shared__ __attribute__((aligned(16))) ushort_t As[128][32];
    __shared__ __attribute__((aligned(16))) ushort_t Bs[64][32];

    const int bid = blockIdx.x;
    const int rid = (bid & 7) * 64 + (bid >> 3);   // XCD-affine bijective (nwg=512)
    const int bm  = rid >> 3, bn = rid & 7;
    const int m0  = bm * 128, n0 = bn * 64;

    const int t    = threadIdx.x;
    const int lane = t & 63;
    const int wv   = t >> 6;
    const int wm   = wv >> 1, wn = wv & 1;
    const int l15  = lane & 15, l16 = lane >> 4;
    const int srow = t >> 2;
    const int scol = (t & 3) * 8;

    f32x4 acc[4][2] = {};

    const ushort_t* a0p = Ap + (size_t)(m0 + srow) * 512 + scol;
    const ushort_t* a1p = a0p + (size_t)64 * 512;
    const ushort_t* b0p = Wb + (size_t)(n0 + srow) * 512 + scol;

#pragma unroll 1
    for (int kt = 0; kt < 16; ++kt) {
        __syncthreads();
        gload16(a0p + kt * 32, (char*)As + wv * 1024);
        gload16(a1p + kt * 32, (char*)As + 4096 + wv * 1024);
        gload16(b0p + kt * 32, (char*)Bs + wv * 1024);
        __syncthreads();

        bf16x8 af[4], bf[2];
#pragma unroll
        for (int i = 0; i < 4; ++i)
            af[i] = *(const bf16x8*)&As[wm * 64 + i * 16 + l15][l16 * 8];
#pragma unroll
        for (int j = 0; j < 2; ++j)
            bf[j] = *(const bf16x8*)&Bs[wn * 32 + j * 16 + l15][l16 * 8];
#pragma unroll
        for (int i = 0; i < 4; ++i)
#pragma unroll
            for (int j = 0; j < 2; ++j)
                acc[i][j] = MFMA16(af[i], bf[j], acc[i][j]);
    }

#pragma unroll
    for (int i = 0; i < 4; ++i)
#pragma unroll
        for (int j = 0; j < 2; ++j) {
            const int n  = n0 + wn * 32 + j * 16 + l15;
            const float bv_ = bias[n];
#pragma unroll
            for (int v = 0; v < 4; ++v) {
                const int m = m0 + wm * 64 + i * 16 + l16 * 4 + v;
                outp[(size_t)m * 512 + n] = acc[i][j][v] + bv_;
            }
        }
}

// ---------------------------------------------------------------------------
// Flash attention, swapped-QK^T 32x32, zero-shift softmax, chunk-ordered K/V
// with global_load_lds staging (bank-conflict-free immediate-offset reads).
// XCD-affine: xcd = id&7 owns 2 bh entirely (per-XCD K/V set = 2MB <= L2).
// l accumulated on the MFMA pipe via all-ones A-fragment (no VALU row-sum,
// no final shuffle); NO launch-bounds pin (r6 lesson: pin => spill).
// ---------------------------------------------------------------------------
__global__ __launch_bounds__(256) void attn_fwd(const ushort_t* __restrict__ Qh,
                                                const ushort_t* __restrict__ Kg,
                                                const ushort_t* __restrict__ Vg,
                                                ushort_t* __restrict__ Out) {
    constexpr int S  = 4096;
    constexpr int NT = 64;
    __shared__ __attribute__((aligned(16))) char LDS[32768];

    const int id   = blockIdx.x;          // 0..511
    const int xcd  = id & 7;
    const int slot = id >> 3;             // 0..63
    const int qt   = slot & 31;
    const int bh   = xcd * 2 + (slot >> 5);
    const int b    = bh >> 3, h = bh & 7;

    const int t    = threadIdx.x;
    const int lane = t & 63;
    const int wv   = t >> 6;
    const int l31  = lane & 31;
    const int hl   = lane >> 5;

    const int qw = qt * 128 + wv * 32;

    // Q fragments (B operand): col=q=l31, k = ds*16 + 8*hl + j
    bf16x8 qf[4];
    {
        const ushort_t* qp = Qh + ((size_t)bh * S + qw + l31) * 64 + hl * 8;
#pragma unroll
        for (int ds = 0; ds < 4; ++ds) qf[ds] = *(const bf16x8*)(qp + ds * 16);
    }

    bf16x8 ones;
#pragma unroll
    for (int j = 0; j < 8; ++j) ones[j] = (short)0x3F80;   // bf16 1.0

    const f32x16 fzero = {};
    f32x16 accO[2] = {};
    f32x16 lacc = {};

    const char* lbase = LDS + lane * 16;   // single loop-invariant read address
    const int wvb = wv * 1024;
    const ushort_t* kg = Kg + (size_t)bh * 262144 + wv * 512 + lane * 8;
    const ushort_t* vg = Vg + (size_t)bh * 262144 + wv * 512 + lane * 8;

    auto issue = [&](int kt, auto curc) {
        constexpr int CUR = decltype(curc)::value;
        const ushort_t* kg_ = kg + (size_t)kt * 4096;
        const ushort_t* vg_ = vg + (size_t)kt * 4096;
        gload16(kg_,        LDS + CUR * 8192 + wvb);
        gload16(kg_ + 2048, LDS + CUR * 8192 + 4096 + wvb);
        gload16(vg_,        LDS + 16384 + CUR * 8192 + wvb);
        gload16(vg_ + 2048, LDS + 16384 + CUR * 8192 + 4096 + wvb);
    };

    auto tile = [&](int kt, auto curc) {
        constexpr int CUR = decltype(curc)::value;

        // QK^T -> S^T[key][q]; C seeded with inline zero
        f32x16 sc0, sc1;
        __builtin_amdgcn_s_setprio(1);
        {
            bf16x8 kf = *(const bf16x8*)(lbase + CUR * 8192);
            sc0 = MFMA32(kf, qf[0], fzero);
        }
#pragma unroll
        for (int ds = 1; ds < 4; ++ds) {
            bf16x8 kf = *(const bf16x8*)(lbase + CUR * 8192 + ds * 1024);
            sc0 = MFMA32(kf, qf[ds], sc0);
        }
        {
            bf16x8 kf = *(const bf16x8*)(lbase + CUR * 8192 + 4096);
            sc1 = MFMA32(kf, qf[0], fzero);
        }
#pragma unroll
        for (int ds = 1; ds < 4; ++ds) {
            bf16x8 kf = *(const bf16x8*)(lbase + CUR * 8192 + 4096 + ds * 1024);
            sc1 = MFMA32(kf, qf[ds], sc1);
        }
        __builtin_amdgcn_s_setprio(0);

        // P = exp2(S)
#pragma unroll
        for (int i = 0; i < 16; ++i) {
            sc0[i] = __builtin_amdgcn_exp2f(sc0[i]);
            sc1[i] = __builtin_amdgcn_exp2f(sc1[i]);
        }

        // pack P^T B-fragments in-register
        bf16x8 pb[4];
#pragma unroll
        for (int ks = 0; ks < 4; ++ks) {
            const int R0 = (ks & 1) * 8;
            float e0, e1, e2, e3, e4, e5, e6, e7;
            if (ks < 2) {
                e0 = sc0[R0+0]; e1 = sc0[R0+1]; e2 = sc0[R0+2]; e3 = sc0[R0+3];
                e4 = sc0[R0+4]; e5 = sc0[R0+5]; e6 = sc0[R0+6]; e7 = sc0[R0+7];
            } else {
                e0 = sc1[R0+0]; e1 = sc1[R0+1]; e2 = sc1[R0+2]; e3 = sc1[R0+3];
                e4 = sc1[R0+4]; e5 = sc1[R0+5]; e6 = sc1[R0+6]; e7 = sc1[R0+7];
            }
            unsigned w0 = cvtpk(e0, e1);
            unsigned w1 = cvtpk(e2, e3);
            unsigned w2 = cvtpk(e4, e5);
            unsigned w3 = cvtpk(e6, e7);
            uint2v s02 = __builtin_amdgcn_permlane32_swap(w0, w2, false, false);
            uint2v s13 = __builtin_amdgcn_permlane32_swap(w1, w3, false, false);
            u32x4 w = {s02.x, s13.x, s02.y, s13.y};
            pb[ks] = __builtin_bit_cast(bf16x8, w);
        }

        // PV: O^T[d][q] += V^T[d][k] * P^T[k][q];  l rides the MFMA pipe
        __builtin_amdgcn_s_setprio(1);
#pragma unroll
        for (int ks = 0; ks < 4; ++ks) {
            {
                bf16x8 vf = *(const bf16x8*)(lbase + 16384 + CUR * 8192 + ks * 1024);
                accO[0] = MFMA32(vf, pb[ks], accO[0]);
            }
            {
                bf16x8 vf = *(const bf16x8*)(lbase + 16384 + CUR * 8192 + 4096 + ks * 1024);
                accO[1] = MFMA32(vf, pb[ks], accO[1]);
            }
            lacc = MFMA32(ones, pb[ks], lacc);
        }
        __builtin_amdgcn_s_setprio(0);

        // all waves done reading buf CUR -> refill it for kt+2
        __syncthreads();
        if (kt + 2 < NT) issue(kt + 2, curc);
    };

    issue(0, ic<0>{});
    issue(1, ic<1>{});
    __syncthreads();   // compiler drains vmcnt here; both buffers ready

#pragma unroll 1
    for (int kt2 = 0; kt2 < NT; kt2 += 2) {
        tile(kt2,     ic<0>{});
        tile(kt2 + 1, ic<1>{});
    }

    // every lacc row equals l(q = l31); both lane halves identical
    const float lt  = lacc[0];
    const float inv = 1.0f / lt;
    ushort_t* orow = Out + ((size_t)b * S + qw + l31) * 512 + h * 64;
#pragma unroll
    for (int db = 0; db < 2; ++db)
#pragma unroll
        for (int q4 = 0; q4 < 4; ++q4) {
            unsigned w0 = cvtpk(accO[db][q4 * 4 + 0] * inv, accO[db][q4 * 4 + 1] * inv);
            unsigned w1 = cvtpk(accO[db][q4 * 4 + 2] * inv, accO[db][q4 * 4 + 3] * inv);
            unsigned tmp[2] = {w0, w1};
            *(us4*)(orow + db * 32 + q4 * 8 + hl * 4) = *(const us4*)tmp;
        }
}

// ---------------------------------------------------------------------------
extern "C" void kernel_launch(void* const* d_in, const int* in_sizes, int n_in,
                              void* d_out, int out_size, void* d_ws, size_t ws_size,
                              hipStream_t stream) {
    const float* q  = (const float*)d_in[0];
    const float* k  = (const float*)d_in[1];
    const float* v  = (const float*)d_in[2];
    const float* Wq = (const float*)d_in[3];
    const float* bq = (const float*)d_in[4];
    const float* bk = (const float*)d_in[6];
    const float* bv = (const float*)d_in[8];
    const float* bo = (const float*)d_in[10];

    char* w = (char*)d_ws;
    const size_t SZ = (size_t)2 * 8 * 4096 * 64 * 2;   // 8 MB per buffer

    ushort_t* Qh  = (ushort_t*)(w);
    ushort_t* Kh  = (ushort_t*)(w + SZ);
    ushort_t* Vtr = (ushort_t*)(w + 2 * SZ);
    ushort_t* AO  = (ushort_t*)(w + 3 * SZ);
    ushort_t* Wb  = (ushort_t*)(w + 4 * SZ);           // 2 MB bf16 weights

    cvt_w<<<dim3(128, 4), 256, 0, stream>>>(Wq, (const float*)d_in[5],
                                            (const float*)d_in[7], (const float*)d_in[9], Wb);

    const float Cs = 0.125f * 1.44269504f;  // softmax scale * log2(e), folded into Q
    gemm_qkv<<<dim3(256, 3), 256, 0, stream>>>(q, k, v, Wb, bq, bk, bv, Qh, Kh, Vtr, Cs);

    attn_fwd<<<512, 256, 0, stream>>>(Qh, Kh, Vtr, AO);

    gemm_out<<<512, 256, 0, stream>>>(AO, Wb + 3 * 262144, bo, (float*)d_out);
}

// Round 12
// 144.582 us; speedup vs baseline: 1.0326x; 1.0217x over previous
//
#include <hip/hip_runtime.h>

typedef short bf16x8 __attribute__((ext_vector_type(8)));
typedef float f32x2 __attribute__((ext_vector_type(2)));
typedef float f32x4 __attribute__((ext_vector_type(4)));
typedef float f32x16 __attribute__((ext_vector_type(16)));
typedef unsigned short ushort_t;
typedef unsigned short us8 __attribute__((ext_vector_type(8)));
typedef unsigned short us4 __attribute__((ext_vector_type(4)));
typedef unsigned int u32x4 __attribute__((ext_vector_type(4)));
typedef unsigned int uint2v __attribute__((ext_vector_type(2)));

#define MFMA16(a, b, c) __builtin_amdgcn_mfma_f32_16x16x32_bf16((a), (b), (c), 0, 0, 0)
#define MFMA32(a, b, c) __builtin_amdgcn_mfma_f32_32x32x16_bf16((a), (b), (c), 0, 0, 0)

template <int N> struct ic { static constexpr int value = N; };

static __device__ __forceinline__ ushort_t f2bf(float f) {
    unsigned int u = __builtin_bit_cast(unsigned int, f);
    u += 0x7FFFu + ((u >> 16) & 1u);   // RNE
    return (ushort_t)(u >> 16);
}

static __device__ __forceinline__ unsigned cvtpk(float lo, float hi) {
    unsigned r;
    asm("v_cvt_pk_bf16_f32 %0, %1, %2" : "=v"(r) : "v"(lo), "v"(hi));
    return r;
}

// global -> LDS direct async copy, 16B per lane (LDS dest = wave-uniform base + lane*16)
static __device__ __forceinline__ void gload16(const void* g, void* l) {
    __builtin_amdgcn_global_load_lds(
        (const __attribute__((address_space(1))) unsigned int*)g,
        (__attribute__((address_space(3))) unsigned int*)l,
        16, 0, 0);
}

// ---------------------------------------------------------------------------
// Convert 4 fp32 512x512 weight matrices to bf16, packed consecutively.
// ---------------------------------------------------------------------------
__global__ __launch_bounds__(256) void cvt_w(const float* __restrict__ W0,
                                             const float* __restrict__ W1,
                                             const float* __restrict__ W2,
                                             const float* __restrict__ W3,
                                             ushort_t* __restrict__ dst) {
    const float* src = (blockIdx.y == 0) ? W0 : (blockIdx.y == 1) ? W1
                     : (blockIdx.y == 2) ? W2 : W3;
    const int i = (blockIdx.x * 256 + threadIdx.x) * 8;
    float4 f0 = *(const float4*)(src + i);
    float4 f1 = *(const float4*)(src + i + 4);
    unsigned tw[4] = {cvtpk(f0.x, f0.y), cvtpk(f0.z, f0.w),
                      cvtpk(f1.x, f1.y), cvtpk(f1.z, f1.w)};
    *(u32x4*)(dst + (size_t)blockIdx.y * 262144 + i) = *(u32x4*)tw;
}

// ---------------------------------------------------------------------------
// Fused Q/K/V projection NT-GEMM (r9-proven 64x64 tile, BK=64, grid (1024,3)).
// y=0: Q -> row-major [B*H][S][64], scaled by Cs.
// y=1: K -> chunk-ordered tiles (attn QK fragment = contiguous 1024B block).
// y=2: V -> chunk-ordered V^T tiles (attn PV fragment = contiguous 1024B).
// ---------------------------------------------------------------------------
__global__ __launch_bounds__(256) void gemm_qkv(const float* __restrict__ qi,
                                                const float* __restrict__ ki,
                                                const float* __restrict__ vi,
                                                const ushort_t* __restrict__ Wball,
                                                const float* __restrict__ bq,
                                                const float* __restrict__ bk,
                                                const float* __restrict__ bv,
                                                ushort_t* __restrict__ Qh,
                                                ushort_t* __restrict__ Kh,
                                                ushort_t* __restrict__ Vt,
                                                float Cs) {
    constexpr int K = 512;
    __shared__ ushort_t As[64][72];
    __shared__ ushort_t Bs[64][72];

    const int which = blockIdx.y;
    const float*    Ap   = (which == 0) ? qi : (which == 1) ? ki : vi;
    const ushort_t* Wb   = Wball + (size_t)which * 262144;
    const float*    bias = (which == 0) ? bq : (which == 1) ? bk : bv;
    ushort_t*       outp = (which == 0) ? Qh : (which == 1) ? Kh : Vt;

    int bid = blockIdx.x;
    bid = (bid & 7) * 128 + (bid >> 3);   // XCD-affine bijective remap (nwg=1024)
    const int bm = bid >> 3;
    const int bn = bid & 7;
    const int m0 = bm * 64, n0 = bn * 64;
    const int t    = threadIdx.x;
    const int lane = t & 63;
    const int wv   = t >> 6;
    const int wm   = wv >> 1, wn = wv & 1;
    const int lrow = t >> 2;
    const int lcol = (t & 3) * 16;

    const int l15 = lane & 15;
    const int l16 = lane >> 4;

    f32x4 acc[2][2] = {};

    const float*    apf = Ap + (size_t)(m0 + lrow) * K + lcol;
    const ushort_t* bpb = Wb + (size_t)(n0 + lrow) * K + lcol;

    us8 br0, br1;
    f32x4 af[4];

    af[0] = *(const f32x4*)apf;       af[1] = *(const f32x4*)(apf + 4);
    af[2] = *(const f32x4*)(apf + 8); af[3] = *(const f32x4*)(apf + 12);
    br0 = *(const us8*)bpb; br1 = *(const us8*)(bpb + 8);

#pragma unroll 1
    for (int kt = 0; kt < K / 64; ++kt) {
        __syncthreads();
        {
            unsigned tw[8];
#pragma unroll
            for (int i = 0; i < 4; ++i) {
                tw[2 * i]     = cvtpk(af[i][0], af[i][1]);
                tw[2 * i + 1] = cvtpk(af[i][2], af[i][3]);
            }
            *(u32x4*)&As[lrow][lcol]     = *(u32x4*)tw;
            *(u32x4*)&As[lrow][lcol + 8] = *(u32x4*)(tw + 4);
        }
        *(us8*)&Bs[lrow][lcol]     = br0;
        *(us8*)&Bs[lrow][lcol + 8] = br1;
        __syncthreads();

        if (kt < K / 64 - 1) {
            const int off = (kt + 1) * 64;
            const float* s = apf + off;
            af[0] = *(const f32x4*)s;       af[1] = *(const f32x4*)(s + 4);
            af[2] = *(const f32x4*)(s + 8); af[3] = *(const f32x4*)(s + 12);
            br0 = *(const us8*)(bpb + off); br1 = *(const us8*)(bpb + off + 8);
        }

#pragma unroll
        for (int kk = 0; kk < 2; ++kk) {
            bf16x8 a0 = *(const bf16x8*)&As[wm * 32 + l15][kk * 32 + l16 * 8];
            bf16x8 a1 = *(const bf16x8*)&As[wm * 32 + 16 + l15][kk * 32 + l16 * 8];
            bf16x8 b0 = *(const bf16x8*)&Bs[wn * 32 + l15][kk * 32 + l16 * 8];
            bf16x8 b1 = *(const bf16x8*)&Bs[wn * 32 + 16 + l15][kk * 32 + l16 * 8];
            acc[0][0] = MFMA16(a0, b0, acc[0][0]);
            acc[0][1] = MFMA16(a0, b1, acc[0][1]);
            acc[1][0] = MFMA16(a1, b0, acc[1][0]);
            acc[1][1] = MFMA16(a1, b1, acc[1][1]);
        }
    }

#pragma unroll
    for (int i = 0; i < 2; ++i)
#pragma unroll
        for (int j = 0; j < 2; ++j) {
            const int n  = n0 + wn * 32 + j * 16 + l15;
            const float bv_ = bias[n];
            const int h = n >> 6, d = n & 63;
            if (which == 2) {
                // V^T chunk-ordered: 4 consecutive keys stay in one 8-chunk
                const int mbase = m0 + wm * 32 + i * 16 + l16 * 4;
                const int b = mbase >> 12, key = mbase & 4095;
                const int keyr = key & 63;
                const int ks = keyr >> 4, hc = (keyr >> 3) & 1, e0 = keyr & 7;
                const int db = d >> 5, dr = d & 31;
                ushort_t tmp[4];
#pragma unroll
                for (int v = 0; v < 4; ++v) tmp[v] = f2bf(acc[i][j][v] + bv_);
                *(us4*)(outp + (size_t)(b * 8 + h) * 262144 +
                        (size_t)(key >> 6) * 4096 +
                        db * 2048 + ks * 512 + (hc * 32 + dr) * 8 + e0) = *(us4*)tmp;
            } else if (which == 1) {
                // K chunk-ordered scalar stores
                const int jd = d >> 4, hc = (d >> 3) & 1, e = d & 7;
#pragma unroll
                for (int v = 0; v < 4; ++v) {
                    const int m = m0 + wm * 32 + i * 16 + l16 * 4 + v;
                    const int b = m >> 12, s = m & 4095;
                    const int r = s & 63, kb2 = r >> 5, kr = r & 31;
                    outp[(size_t)(b * 8 + h) * 262144 + (size_t)(s >> 6) * 4096 +
                         kb2 * 2048 + jd * 512 + (hc * 32 + kr) * 8 + e] =
                        f2bf(acc[i][j][v] + bv_);
                }
            } else {
#pragma unroll
                for (int v = 0; v < 4; ++v) {
                    const int m = m0 + wm * 32 + i * 16 + l16 * 4 + v;
                    const int b = m >> 12, s = m & 4095;
                    outp[(((size_t)(b * 8 + h)) * 4096 + s) * 64 + d] =
                        f2bf((acc[i][j][v] + bv_) * Cs);
                }
            }
        }
}

// ---------------------------------------------------------------------------
// Output NT-GEMM (r9-proven): A bf16 [M][512], W bf16, out fp32 [M][512].
// ---------------------------------------------------------------------------
__global__ __launch_bounds__(256) void gemm_out(const ushort_t* __restrict__ Ap,
                                                const ushort_t* __restrict__ Wb,
                                                const float* __restrict__ bias,
                                                float* __restrict__ outp) {
    constexpr int K = 512;
    __shared__ ushort_t As[64][72];
    __shared__ ushort_t Bs[64][72];

    int bid = blockIdx.x;
    bid = (bid & 7) * 128 + (bid >> 3);
    const int bm = bid >> 3;
    const int bn = bid & 7;
    const int m0 = bm * 64, n0 = bn * 64;
    const int t    = threadIdx.x;
    const int lane = t & 63;
    const int wv   = t >> 6;
    const int wm   = wv >> 1, wn = wv & 1;
    const int lrow = t >> 2;
    const int lcol = (t & 3) * 16;

    const int l15 = lane & 15;
    const int l16 = lane >> 4;

    f32x4 acc[2][2] = {};

    const ushort_t* apb = Ap + (size_t)(m0 + lrow) * K + lcol;
    const ushort_t* bpb = Wb + (size_t)(n0 + lrow) * K + lcol;

    us8 ar0, ar1, br0, br1;
    ar0 = *(const us8*)apb; ar1 = *(const us8*)(apb + 8);
    br0 = *(const us8*)bpb; br1 = *(const us8*)(bpb + 8);

#pragma unroll 1
    for (int kt = 0; kt < K / 64; ++kt) {
        __syncthreads();
        *(us8*)&As[lrow][lcol]     = ar0;
        *(us8*)&As[lrow][lcol + 8] = ar1;
        *(us8*)&Bs[lrow][lcol]     = br0;
        *(us8*)&Bs[lrow][lcol + 8] = br1;
        __syncthreads();

        if (kt < K / 64 - 1) {
            const int off = (kt + 1) * 64;
            ar0 = *(const us8*)(apb + off); ar1 = *(const us8*)(apb + off + 8);
            br0 = *(const us8*)(bpb + off); br1 = *(const us8*)(bpb + off + 8);
        }

#pragma unroll
        for (int kk = 0; kk < 2; ++kk) {
            bf16x8 a0 = *(const bf16x8*)&As[wm * 32 + l15][kk * 32 + l16 * 8];
            bf16x8 a1 = *(const bf16x8*)&As[wm * 32 + 16 + l15][kk * 32 + l16 * 8];
            bf16x8 b0 = *(const bf16x8*)&Bs[wn * 32 + l15][kk * 32 + l16 * 8];
            bf16x8 b1 = *(const bf16x8*)&Bs[wn * 32 + 16 + l15][kk * 32 + l16 * 8];
            acc[0][0] = MFMA16(a0, b0, acc[0][0]);
            acc[0][1] = MFMA16(a0, b1, acc[0][1]);
            acc[1][0] = MFMA16(a1, b0, acc[1][0]);
            acc[1][1] = MFMA16(a1, b1, acc[1][1]);
        }
    }

#pragma unroll
    for (int i = 0; i < 2; ++i)
#pragma unroll
        for (int j = 0; j < 2; ++j) {
            const int n  = n0 + wn * 32 + j * 16 + l15;
            const float bv_ = bias[n];
#pragma unroll
            for (int v = 0; v < 4; ++v) {
                const int m = m0 + wm * 32 + i * 16 + l16 * 4 + v;
                outp[(size_t)m * 512 + n] = acc[i][j][v] + bv_;
            }
        }
}

// ---------------------------------------------------------------------------
// Flash attention, swapped-QK^T 32x32, zero-shift softmax, Qw=64 per wave.
// Each wave owns TWO 32-query groups so every kf/vf LDS fragment read feeds
// 2 MFMAs — LDS read bytes per FLOP halved (the r9-r11 plateau was LDS-BW).
// Grid 256 blocks (16 qt x 16 bh) = 1 block/CU; xcd = id&7 owns 2 bh
// (per-XCD K/V working set 2MB <= L2). K/V chunk-ordered in global,
// global_load_lds staging, conflict-free immediate-offset ds_read_b128.
// ---------------------------------------------------------------------------
__global__ __launch_bounds__(256) void attn_fwd(const ushort_t* __restrict__ Qh,
                                                const ushort_t* __restrict__ Kg,
                                                const ushort_t* __restrict__ Vg,
                                                ushort_t* __restrict__ Out) {
    constexpr int S  = 4096;
    constexpr int NT = 64;
    __shared__ __attribute__((aligned(16))) char LDS[32768];

    const int id   = blockIdx.x;          // 0..255
    const int xcd  = id & 7;
    const int slot = id >> 3;             // 0..31
    const int qt   = slot & 15;
    const int bh   = xcd * 2 + (slot >> 4);
    const int b    = bh >> 3, h = bh & 7;

    const int t    = threadIdx.x;
    const int lane = t & 63;
    const int wv   = t >> 6;
    const int l31  = lane & 31;
    const int hl   = lane >> 5;

    const int qw = qt * 256 + wv * 64;    // wave's 64 queries

    // Q fragments (B operand), two 32-q groups: col=q=l31, k = ds*16+8*hl+j
    bf16x8 qf[2][4];
#pragma unroll
    for (int g = 0; g < 2; ++g) {
        const ushort_t* qp = Qh + ((size_t)bh * S + qw + g * 32 + l31) * 64 + hl * 8;
#pragma unroll
        for (int ds = 0; ds < 4; ++ds) qf[g][ds] = *(const bf16x8*)(qp + ds * 16);
    }

    const f32x16 fzero = {};
    f32x16 accO[2][2] = {};       // [g][db]
    float ll[2] = {0.f, 0.f};

    const char* lbase = LDS + lane * 16;
    const int wvb = wv * 1024;
    const ushort_t* kg = Kg + (size_t)bh * 262144 + wv * 512 + lane * 8;
    const ushort_t* vg = Vg + (size_t)bh * 262144 + wv * 512 + lane * 8;

    auto issue = [&](int kt, auto curc) {
        constexpr int CUR = decltype(curc)::value;
        const ushort_t* kg_ = kg + (size_t)kt * 4096;
        const ushort_t* vg_ = vg + (size_t)kt * 4096;
        gload16(kg_,        LDS + CUR * 8192 + wvb);
        gload16(kg_ + 2048, LDS + CUR * 8192 + 4096 + wvb);
        gload16(vg_,        LDS + 16384 + CUR * 8192 + wvb);
        gload16(vg_ + 2048, LDS + 16384 + CUR * 8192 + 4096 + wvb);
    };

    auto tile = [&](int kt, auto curc) {
        constexpr int CUR = decltype(curc)::value;

        // QK^T: each kf read feeds both q-groups
        f32x16 sc[2][2];          // [g][kb]
        __builtin_amdgcn_s_setprio(1);
#pragma unroll
        for (int kb = 0; kb < 2; ++kb) {
            {
                bf16x8 kf = *(const bf16x8*)(lbase + CUR * 8192 + kb * 4096);
                sc[0][kb] = MFMA32(kf, qf[0][0], fzero);
                sc[1][kb] = MFMA32(kf, qf[1][0], fzero);
            }
#pragma unroll
            for (int ds = 1; ds < 4; ++ds) {
                bf16x8 kf = *(const bf16x8*)(lbase + CUR * 8192 + kb * 4096 + ds * 1024);
                sc[0][kb] = MFMA32(kf, qf[0][ds], sc[0][kb]);
                sc[1][kb] = MFMA32(kf, qf[1][ds], sc[1][kb]);
            }
        }
        __builtin_amdgcn_s_setprio(0);

        // P = exp2(S)
#pragma unroll
        for (int g = 0; g < 2; ++g)
#pragma unroll
            for (int kb = 0; kb < 2; ++kb)
#pragma unroll
                for (int i = 0; i < 16; ++i)
                    sc[g][kb][i] = __builtin_amdgcn_exp2f(sc[g][kb][i]);

        // l partial sums via packed-pair tree
#pragma unroll
        for (int g = 0; g < 2; ++g) {
#define PAIR(v, i) __builtin_shufflevector((v), (v), 2 * (i), 2 * (i) + 1)
            f32x2 pa  = (PAIR(sc[g][0], 0) + PAIR(sc[g][0], 1)) + (PAIR(sc[g][0], 2) + PAIR(sc[g][0], 3));
            f32x2 pbt = (PAIR(sc[g][0], 4) + PAIR(sc[g][0], 5)) + (PAIR(sc[g][0], 6) + PAIR(sc[g][0], 7));
            f32x2 pc  = (PAIR(sc[g][1], 0) + PAIR(sc[g][1], 1)) + (PAIR(sc[g][1], 2) + PAIR(sc[g][1], 3));
            f32x2 pd  = (PAIR(sc[g][1], 4) + PAIR(sc[g][1], 5)) + (PAIR(sc[g][1], 6) + PAIR(sc[g][1], 7));
            f32x2 s2  = (pa + pbt) + (pc + pd);
            ll[g] += s2.x + s2.y;
#undef PAIR
        }

        // pack P^T B-fragments in-register
        bf16x8 pb[2][4];
#pragma unroll
        for (int g = 0; g < 2; ++g)
#pragma unroll
            for (int ks = 0; ks < 4; ++ks) {
                const int kb = ks >> 1, R0 = (ks & 1) * 8;
                unsigned w0 = cvtpk(sc[g][kb][R0 + 0], sc[g][kb][R0 + 1]);
                unsigned w1 = cvtpk(sc[g][kb][R0 + 2], sc[g][kb][R0 + 3]);
                unsigned w2 = cvtpk(sc[g][kb][R0 + 4], sc[g][kb][R0 + 5]);
                unsigned w3 = cvtpk(sc[g][kb][R0 + 6], sc[g][kb][R0 + 7]);
                uint2v s02 = __builtin_amdgcn_permlane32_swap(w0, w2, false, false);
                uint2v s13 = __builtin_amdgcn_permlane32_swap(w1, w3, false, false);
                u32x4 w = {s02.x, s13.x, s02.y, s13.y};
                pb[g][ks] = __builtin_bit_cast(bf16x8, w);
            }

        // PV: each vf read feeds both q-groups
        __builtin_amdgcn_s_setprio(1);
#pragma unroll
        for (int ks = 0; ks < 4; ++ks)
#pragma unroll
            for (int db = 0; db < 2; ++db) {
                bf16x8 vf = *(const bf16x8*)(lbase + 16384 + CUR * 8192 + db * 4096 + ks * 1024);
                accO[0][db] = MFMA32(vf, pb[0][ks], accO[0][db]);
                accO[1][db] = MFMA32(vf, pb[1][ks], accO[1][db]);
            }
        __builtin_amdgcn_s_setprio(0);

        // all waves done reading buf CUR -> refill it for kt+2
        __syncthreads();
        if (kt + 2 < NT) issue(kt + 2, curc);
    };

    issue(0, ic<0>{});
    issue(1, ic<1>{});
    __syncthreads();   // compiler drains vmcnt here; both buffers ready

#pragma unroll 1
    for (int kt2 = 0; kt2 < NT; kt2 += 2) {
        tile(kt2,     ic<0>{});
        tile(kt2 + 1, ic<1>{});
    }

#pragma unroll
    for (int g = 0; g < 2; ++g) {
        const float lt  = ll[g] + __shfl_xor(ll[g], 32);
        const float inv = 1.0f / lt;
        ushort_t* orow = Out + ((size_t)b * S + qw + g * 32 + l31) * 512 + h * 64;
#pragma unroll
        for (int db = 0; db < 2; ++db)
#pragma unroll
            for (int q4 = 0; q4 < 4; ++q4) {
                unsigned w0 = cvtpk(accO[g][db][q4 * 4 + 0] * inv, accO[g][db][q4 * 4 + 1] * inv);
                unsigned w1 = cvtpk(accO[g][db][q4 * 4 + 2] * inv, accO[g][db][q4 * 4 + 3] * inv);
                unsigned tmp[2] = {w0, w1};
                *(us4*)(orow + db * 32 + q4 * 8 + hl * 4) = *(const us4*)tmp;
            }
    }
}

// ---------------------------------------------------------------------------
extern "C" void kernel_launch(void* const* d_in, const int* in_sizes, int n_in,
                              void* d_out, int out_size, void* d_ws, size_t ws_size,
                              hipStream_t stream) {
    const float* q  = (const float*)d_in[0];
    const float* k  = (const float*)d_in[1];
    const float* v  = (const float*)d_in[2];
    const float* Wq = (const float*)d_in[3];
    const float* bq = (const float*)d_in[4];
    const float* bk = (const float*)d_in[6];
    const float* bv = (const float*)d_in[8];
    const float* bo = (const float*)d_in[10];

    char* w = (char*)d_ws;
    const size_t SZ = (size_t)2 * 8 * 4096 * 64 * 2;   // 8 MB per buffer

    ushort_t* Qh  = (ushort_t*)(w);
    ushort_t* Kh  = (ushort_t*)(w + SZ);
    ushort_t* Vtr = (ushort_t*)(w + 2 * SZ);
    ushort_t* AO  = (ushort_t*)(w + 3 * SZ);
    ushort_t* Wb  = (ushort_t*)(w + 4 * SZ);           // 2 MB bf16 weights

    cvt_w<<<dim3(128, 4), 256, 0, stream>>>(Wq, (const float*)d_in[5],
                                            (const float*)d_in[7], (const float*)d_in[9], Wb);

    const float Cs = 0.125f * 1.44269504f;  // softmax scale * log2(e), folded into Q
    gemm_qkv<<<dim3(1024, 3), 256, 0, stream>>>(q, k, v, Wb, bq, bk, bv, Qh, Kh, Vtr, Cs);

    attn_fwd<<<256, 256, 0, stream>>>(Qh, Kh, Vtr, AO);

    gemm_out<<<1024, 256, 0, stream>>>(AO, Wb + 3 * 262144, bo, (float*)d_out);
}